// Round 1
// baseline (528.247 us; speedup 1.0000x reference)
//
#include <hip/hip_runtime.h>

#define N_BINS 15
#define NCLASS 100

// Pass 1: one wave per row. Compute per-row (max, argmax, sum-exp) ->
// confidence, accuracy, bin; accumulate per-bin {count, conf_sum, acc_sum}
// in LDS, flush once per block to global accumulators in d_ws.
__global__ __launch_bounds__(256) void ece_pass1(
    const float* __restrict__ logits,
    const int* __restrict__ labels,
    float* __restrict__ bins,   // [3 * N_BINS] global accumulators (zeroed)
    int n_rows)
{
    __shared__ float s_cnt[N_BINS], s_conf[N_BINS], s_acc[N_BINS];
    const int tid = threadIdx.x;
    if (tid < N_BINS) { s_cnt[tid] = 0.f; s_conf[tid] = 0.f; s_acc[tid] = 0.f; }
    __syncthreads();

    const int lane = tid & 63;
    const int wave_in_block = tid >> 6;                 // 0..3
    const int waves_total = (gridDim.x * blockDim.x) >> 6;
    const int wave_id = blockIdx.x * 4 + wave_in_block;

    for (int row = wave_id; row < n_rows; row += waves_total) {
        const float* rp = logits + (size_t)row * NCLASS;

        // lanes 0..49 each own 2 consecutive elements (float2, 8B coalesced)
        float x0 = -INFINITY, x1 = -INFINITY;
        if (lane < NCLASS / 2) {
            float2 f = *reinterpret_cast<const float2*>(rp + 2 * lane);
            x0 = f.x; x1 = f.y;
        }

        // local (max, first-index)
        float v; int idx;
        if (x1 > x0) { v = x1; idx = 2 * lane + 1; }
        else         { v = x0; idx = 2 * lane; }

        // wave butterfly: max value, tie -> smallest index (matches jnp.argmax)
        #pragma unroll
        for (int off = 32; off; off >>= 1) {
            float ov = __shfl_xor(v, off, 64);
            int   oi = __shfl_xor(idx, off, 64);
            if (ov > v || (ov == v && oi < idx)) { v = ov; idx = oi; }
        }

        // sum of exp(x - max); max element contributes exp(0) == 1 exactly
        float s = 0.f;
        if (lane < NCLASS / 2) s = __expf(x0 - v) + __expf(x1 - v);
        #pragma unroll
        for (int off = 32; off; off >>= 1)
            s += __shfl_xor(s, off, 64);

        if (lane == 0) {
            float conf = 1.0f / s;                       // = max softmax prob
            int b = (int)ceilf(conf * (float)N_BINS) - 1; // torch-style bins
            b = min(max(b, 0), N_BINS - 1);
            float acc = (idx == labels[row]) ? 1.0f : 0.0f;
            atomicAdd(&s_cnt[b], 1.0f);
            atomicAdd(&s_conf[b], conf);
            atomicAdd(&s_acc[b], acc);
        }
    }

    __syncthreads();
    if (tid < N_BINS) {
        atomicAdd(&bins[tid],              s_cnt[tid]);
        atomicAdd(&bins[N_BINS + tid],     s_conf[tid]);
        atomicAdd(&bins[2 * N_BINS + tid], s_acc[tid]);
    }
}

// Pass 2: fold 15 bins into the scalar ECE.
__global__ void ece_final(const float* __restrict__ bins,
                          float* __restrict__ out, float n)
{
    if (threadIdx.x == 0) {
        float ece = 0.f;
        for (int i = 0; i < N_BINS; ++i) {
            float cnt = bins[i];
            if (cnt > 0.f) {
                float sc  = fmaxf(cnt, 1.0f);
                float gap = fabsf(bins[N_BINS + i] / sc - bins[2 * N_BINS + i] / sc);
                ece += gap * (cnt / n);
            }
        }
        out[0] = ece;
    }
}

extern "C" void kernel_launch(void* const* d_in, const int* in_sizes, int n_in,
                              void* d_out, int out_size, void* d_ws, size_t ws_size,
                              hipStream_t stream)
{
    const float* logits = (const float*)d_in[0];
    const int*   labels = (const int*)d_in[1];
    float* out  = (float*)d_out;
    float* bins = (float*)d_ws;

    const int n_rows = in_sizes[1];   // N = 2097152 (labels count)

    hipMemsetAsync(bins, 0, 3 * N_BINS * sizeof(float), stream);

    // 2048 blocks x 256 thr = 8192 waves; grid-stride, ~256 rows/wave.
    ece_pass1<<<2048, 256, 0, stream>>>(logits, labels, bins, n_rows);
    ece_final<<<1, 64, 0, stream>>>(bins, out, (float)n_rows);
}

// Round 2
// 226.238 us; speedup vs baseline: 2.3349x; 2.3349x over previous
//
#include <hip/hip_runtime.h>

#define N_BINS 15
#define NCLASS 100          // 25 float4 per row
#define ROWS_PER_BLOCK 64   // 256 threads / 4 threads-per-row

// Quad-per-row: threads (row, q) with q=0..3; thread q scans float4 indices
// q, q+4, ..., <25 of its row directly from global (64B-contiguous per row
// per load instruction -> line reuse distance 1). Single pass computes
// (max, argmax, sum exp(x)); conf = exp(max)/sum. Per-row stats go to a
// per-slot private LDS histogram (no atomics in hot loop), folded at exit.
__global__ __launch_bounds__(256) void ece_pass1(
    const float* __restrict__ logits,
    const int* __restrict__ labels,
    float* __restrict__ bins,   // [45] global accumulators (zeroed)
    int n_rows)
{
    __shared__ float priv[ROWS_PER_BLOCK * 45];   // [slot][0..14]=cnt,[15..29]=conf,[30..44]=acc
    const int tid = threadIdx.x;

    for (int k = tid; k < ROWS_PER_BLOCK * 45; k += 256) priv[k] = 0.f;
    __syncthreads();

    const int q    = tid & 3;
    const int slot = tid >> 2;                      // 0..63, private row slot
    const int rows_per_iter = gridDim.x * ROWS_PER_BLOCK;

    for (int row = blockIdx.x * ROWS_PER_BLOCK + slot; row < n_rows;
         row += rows_per_iter) {
        const float* rp = logits + (size_t)row * NCLASS;

        float vmax = -INFINITY; int vidx = 0; float s = 0.f;
        #pragma unroll
        for (int i = 0; i < 7; ++i) {
            int j = q + 4 * i;                      // float4 index within row
            if (j < NCLASS / 4) {
                float4 f = *reinterpret_cast<const float4*>(rp + 4 * j);
                int e = 4 * j;
                if (f.x > vmax) { vmax = f.x; vidx = e; }
                if (f.y > vmax) { vmax = f.y; vidx = e + 1; }
                if (f.z > vmax) { vmax = f.z; vidx = e + 2; }
                if (f.w > vmax) { vmax = f.w; vidx = e + 3; }
                s += __expf(f.x) + __expf(f.y) + __expf(f.z) + __expf(f.w);
            }
        }

        // quad reduction (lanes t^1, t^2 stay within the quad)
        #pragma unroll
        for (int off = 1; off <= 2; off <<= 1) {
            float ov = __shfl_xor(vmax, off, 64);
            int   oi = __shfl_xor(vidx, off, 64);
            float os = __shfl_xor(s, off, 64);
            s += os;
            if (ov > vmax || (ov == vmax && oi < vidx)) { vmax = ov; vidx = oi; }
        }

        if (q == 0) {
            float conf = __expf(vmax) / s;            // = max softmax prob
            int b = (int)ceilf(conf * (float)N_BINS) - 1;
            b = min(max(b, 0), N_BINS - 1);
            float acc = (vidx == labels[row]) ? 1.0f : 0.0f;
            float* pb = &priv[slot * 45];
            pb[b]      += 1.0f;
            pb[15 + b] += conf;
            pb[30 + b] += acc;
        }
    }

    __syncthreads();
    // fold 64 private slots -> 45 block totals -> global atomics
    if (tid < 45) {
        float v = 0.f;
        #pragma unroll 8
        for (int sIdx = 0; sIdx < ROWS_PER_BLOCK; ++sIdx)
            v += priv[sIdx * 45 + tid];
        atomicAdd(&bins[tid], v);
    }
}

// Pass 2: fold 15 bins into the scalar ECE.
__global__ void ece_final(const float* __restrict__ bins,
                          float* __restrict__ out, float n)
{
    if (threadIdx.x == 0) {
        float ece = 0.f;
        for (int i = 0; i < N_BINS; ++i) {
            float cnt = bins[i];
            if (cnt > 0.f) {
                float sc  = fmaxf(cnt, 1.0f);
                float gap = fabsf(bins[15 + i] / sc - bins[30 + i] / sc);
                ece += gap * (cnt / n);
            }
        }
        out[0] = ece;
    }
}

extern "C" void kernel_launch(void* const* d_in, const int* in_sizes, int n_in,
                              void* d_out, int out_size, void* d_ws, size_t ws_size,
                              hipStream_t stream)
{
    const float* logits = (const float*)d_in[0];
    const int*   labels = (const int*)d_in[1];
    float* out  = (float*)d_out;
    float* bins = (float*)d_ws;

    const int n_rows = in_sizes[1];   // N = 2097152

    hipMemsetAsync(bins, 0, 45 * sizeof(float), stream);

    // 2048 blocks x 64 rows/block-iter = 131072 rows/sweep; 16 sweeps.
    ece_pass1<<<2048, 256, 0, stream>>>(logits, labels, bins, n_rows);
    ece_final<<<1, 64, 0, stream>>>(bins, out, (float)n_rows);
}

// Round 3
// 163.871 us; speedup vs baseline: 3.2236x; 1.3806x over previous
//
#include <hip/hip_runtime.h>

typedef float f32x4 __attribute__((ext_vector_type(4)));

#define N_BINS 15
#define NCLASS 100          // 25 float4 per row
#define ROWS_PER_BLOCK 64   // 256 threads / 4 threads-per-row

// Quad-per-row streaming pass. Thread q of a quad scans float4 indices
// q, q+4, ..., q+20 (+ index 24 on q==0 via sentinel trick). Computes
// row max and sum(exp(x)) with 4 independent chains each; accuracy via
// the label-probe trick (pred==label  <=>  logits[row][label] == rowmax),
// so no argmax index tracking at all. Per-slot private LDS bins, folded
// once per block.
__global__ __launch_bounds__(256) void ece_pass1(
    const float* __restrict__ logits,
    const int* __restrict__ labels,
    float* __restrict__ bins,   // [45] global accumulators (zeroed)
    int n_rows)
{
    __shared__ float priv[ROWS_PER_BLOCK * 45];
    const int tid = threadIdx.x;
    for (int k = tid; k < ROWS_PER_BLOCK * 45; k += 256) priv[k] = 0.f;
    __syncthreads();

    const int q    = tid & 3;
    const int slot = tid >> 2;                  // 0..63 private row slot
    const int stride = gridDim.x * ROWS_PER_BLOCK;
    float* pb = &priv[slot * 45];

    for (int row = blockIdx.x * ROWS_PER_BLOCK + slot; row < n_rows;
         row += stride) {
        const float* rp = logits + (size_t)row * NCLASS;
        const f32x4* rv = (const f32x4*)rp;

        // 6 unconditional 16B loads per thread (quad covers 64B/instr)
        f32x4 F[6];
        #pragma unroll
        for (int i = 0; i < 6; ++i) F[i] = rv[q + 4 * i];

        // tail float4 (elements 96..99): only q==0 loads; others keep a
        // sentinel that is fmax-neutral and exp-underflows to 0.
        f32x4 T = { -1e30f, -1e30f, -1e30f, -1e30f };
        if (q == 0) T = rv[24];

        int lab = 0;
        if (q == 0) lab = labels[row];

        // 4 independent max chains + 4 independent sum-exp chains
        f32x4 m4 = F[0];
        f32x4 s4;
        s4.x = __expf(F[0].x); s4.y = __expf(F[0].y);
        s4.z = __expf(F[0].z); s4.w = __expf(F[0].w);
        #pragma unroll
        for (int i = 1; i < 6; ++i) {
            m4.x = fmaxf(m4.x, F[i].x); m4.y = fmaxf(m4.y, F[i].y);
            m4.z = fmaxf(m4.z, F[i].z); m4.w = fmaxf(m4.w, F[i].w);
            s4.x += __expf(F[i].x); s4.y += __expf(F[i].y);
            s4.z += __expf(F[i].z); s4.w += __expf(F[i].w);
        }
        m4.x = fmaxf(m4.x, T.x); m4.y = fmaxf(m4.y, T.y);
        m4.z = fmaxf(m4.z, T.z); m4.w = fmaxf(m4.w, T.w);
        s4.x += __expf(T.x); s4.y += __expf(T.y);
        s4.z += __expf(T.z); s4.w += __expf(T.w);

        float vm = fmaxf(fmaxf(m4.x, m4.y), fmaxf(m4.z, m4.w));
        float ss = (s4.x + s4.y) + (s4.z + s4.w);

        // label probe: the row was just streamed -> L1-resident line
        float pv = 0.f;
        if (q == 0) pv = rp[lab];

        // quad reduction, width 4 -> DPP quad_perm, stays on VALU pipe
        #pragma unroll
        for (int off = 1; off <= 2; off <<= 1) {
            ss += __shfl_xor(ss, off, 4);
            vm = fmaxf(vm, __shfl_xor(vm, off, 4));
        }

        if (q == 0) {
            float conf = __expf(vm) / ss;            // = max softmax prob
            int b = (int)ceilf(conf * (float)N_BINS) - 1;
            b = min(max(b, 0), N_BINS - 1);
            pb[b]      += 1.0f;
            pb[15 + b] += conf;
            pb[30 + b] += (pv == vm) ? 1.0f : 0.0f;
        }
    }

    __syncthreads();
    // fold 64 private slots -> 45 block totals -> global atomics
    if (tid < 45) {
        float v = 0.f;
        #pragma unroll 8
        for (int s = 0; s < ROWS_PER_BLOCK; ++s)
            v += priv[s * 45 + tid];
        atomicAdd(&bins[tid], v);
    }
}

// Pass 2: fold 15 bins into the scalar ECE.
__global__ void ece_final(const float* __restrict__ bins,
                          float* __restrict__ out, float n)
{
    if (threadIdx.x == 0) {
        float ece = 0.f;
        for (int i = 0; i < N_BINS; ++i) {
            float cnt = bins[i];
            if (cnt > 0.f) {
                float sc  = fmaxf(cnt, 1.0f);
                float gap = fabsf(bins[15 + i] / sc - bins[30 + i] / sc);
                ece += gap * (cnt / n);
            }
        }
        out[0] = ece;
    }
}

extern "C" void kernel_launch(void* const* d_in, const int* in_sizes, int n_in,
                              void* d_out, int out_size, void* d_ws, size_t ws_size,
                              hipStream_t stream)
{
    const float* logits = (const float*)d_in[0];
    const int*   labels = (const int*)d_in[1];
    float* out  = (float*)d_out;
    float* bins = (float*)d_ws;

    const int n_rows = in_sizes[1];   // N = 2097152

    hipMemsetAsync(bins, 0, 45 * sizeof(float), stream);

    // 2048 blocks x 64 rows = 131072 rows/sweep; 16 sweeps, grid-stride.
    ece_pass1<<<2048, 256, 0, stream>>>(logits, labels, bins, n_rows);
    ece_final<<<1, 64, 0, stream>>>(bins, out, (float)n_rows);
}

// Round 4
// 160.944 us; speedup vs baseline: 3.2822x; 1.0182x over previous
//
#include <hip/hip_runtime.h>

typedef float f32x4 __attribute__((ext_vector_type(4)));

typedef __attribute__((address_space(1))) const void global_cv;
typedef __attribute__((address_space(3))) void lds_v;

#define N_BINS 15
#define NCLASS 100
#define ROWS   64                 // rows staged per block-iteration
#define GRID   768                // 3 blocks/CU * 256 CUs (LDS-resident exactly)

// Pass 1 with async linear staging:
//  - global -> LDS via global_load_lds width=16: each block-iteration stages a
//    contiguous, 128B-aligned 25600B chunk (64 rows) with perfectly linear
//    16B/lane requests (identical pattern to the 6.3 TB/s copy ubench).
//  - double-buffered; stage(g+1) issued right after the barrier so HBM stays
//    busy during compute(g) and during the barrier drain.
//  - compute: quad-per-row from LDS (ds_read_b128, baseline bank structure),
//    label probe from LDS (no dependent global load), block bins via LDS
//    atomics (contention hidden under the ~7500-cycle memory period).
__global__ __launch_bounds__(256) void ece_pass1(
    const float* __restrict__ logits,
    const int* __restrict__ labels,
    float* __restrict__ bins,   // [45] global accumulators (zeroed)
    int n_rows, int niter)
{
    __shared__ __align__(16) float stage[2][ROWS * NCLASS];  // 2 x 25600 B
    __shared__ float priv[45];

    const int tid  = threadIdx.x;
    const int wave = tid >> 6;
    const int q    = tid & 3;
    const int slot = tid >> 2;                 // 0..63 -> row within chunk

    if (tid < 45) priv[tid] = 0.f;

    const long max_slot = (long)n_rows * (NCLASS / 4) - 1;
    const f32x4* gv = (const f32x4*)logits;

    // stage one 64-row chunk into stage[buf]; linear 16B/lane, wave-uniform
    // LDS base + lane*16 (global_load_lds requirement).
    auto issue_stage = [&](int buf, long row0) {
        if (row0 >= n_rows) return;
        const long s0 = row0 * (NCLASS / 4);
        #pragma unroll
        for (int r = 0; r < 6; ++r) {          // slots 0..1535
            long si = s0 + r * 256 + tid;
            if (si > max_slot) si = max_slot;  // clamp: junk, never consumed
            __builtin_amdgcn_global_load_lds(
                (global_cv*)(gv + si),
                (lds_v*)&stage[buf][(r * 256 + wave * 64) * 4],
                16, 0, 0);
        }
        if (wave == 0) {                       // slots 1536..1599 (one wave)
            long si = s0 + 1536 + tid;
            if (si > max_slot) si = max_slot;
            __builtin_amdgcn_global_load_lds(
                (global_cv*)(gv + si),
                (lds_v*)&stage[buf][1536 * 4],
                16, 0, 0);
        }
    };

    issue_stage(0, (long)blockIdx.x * ROWS);

    for (int g = 0; g < niter; ++g) {
        // drain (stage g landed for all waves) + compute(g-1) finished
        __syncthreads();
        if (g + 1 < niter)
            issue_stage((g + 1) & 1,
                        ((long)(g + 1) * gridDim.x + blockIdx.x) * ROWS);

        const long row = ((long)g * gridDim.x + blockIdx.x) * ROWS + slot;
        const float* rp = &stage[g & 1][slot * NCLASS];
        const f32x4* rv = (const f32x4*)rp;

        int lab = 0;
        if (q == 0 && row < n_rows) lab = labels[row];

        // 6 ds_read_b128 per thread (quad covers 64B of the row per i)
        f32x4 F[6];
        #pragma unroll
        for (int i = 0; i < 6; ++i) F[i] = rv[q + 4 * i];

        // tail float4 (elements 96..99): q==0 real, others fmax/exp-neutral
        f32x4 T = { -1e30f, -1e30f, -1e30f, -1e30f };
        if (q == 0) T = rv[24];

        // 4 independent max chains + 4 independent sum-exp chains
        f32x4 m4 = F[0];
        f32x4 s4;
        s4.x = __expf(F[0].x); s4.y = __expf(F[0].y);
        s4.z = __expf(F[0].z); s4.w = __expf(F[0].w);
        #pragma unroll
        for (int i = 1; i < 6; ++i) {
            m4.x = fmaxf(m4.x, F[i].x); m4.y = fmaxf(m4.y, F[i].y);
            m4.z = fmaxf(m4.z, F[i].z); m4.w = fmaxf(m4.w, F[i].w);
            s4.x += __expf(F[i].x); s4.y += __expf(F[i].y);
            s4.z += __expf(F[i].z); s4.w += __expf(F[i].w);
        }
        m4.x = fmaxf(m4.x, T.x); m4.y = fmaxf(m4.y, T.y);
        m4.z = fmaxf(m4.z, T.z); m4.w = fmaxf(m4.w, T.w);
        s4.x += __expf(T.x); s4.y += __expf(T.y);
        s4.z += __expf(T.z); s4.w += __expf(T.w);

        float vm = fmaxf(fmaxf(m4.x, m4.y), fmaxf(m4.z, m4.w));
        float ss = (s4.x + s4.y) + (s4.z + s4.w);

        // label probe from LDS (pred==label <=> logits[row][label]==rowmax)
        float pv = 0.f;
        if (q == 0) pv = rp[lab];

        // quad reduction, width 4 -> DPP quad_perm
        #pragma unroll
        for (int off = 1; off <= 2; off <<= 1) {
            ss += __shfl_xor(ss, off, 4);
            vm = fmaxf(vm, __shfl_xor(vm, off, 4));
        }

        if (q == 0 && row < n_rows) {
            float conf = __expf(vm) / ss;           // = max softmax prob
            int b = (int)ceilf(conf * (float)N_BINS) - 1;
            b = min(max(b, 0), N_BINS - 1);
            atomicAdd(&priv[b],      1.0f);
            atomicAdd(&priv[15 + b], conf);
            atomicAdd(&priv[30 + b], (pv == vm) ? 1.0f : 0.0f);
        }
    }

    __syncthreads();
    if (tid < 45) atomicAdd(&bins[tid], priv[tid]);
}

// Pass 2: fold 15 bins into the scalar ECE.
__global__ void ece_final(const float* __restrict__ bins,
                          float* __restrict__ out, float n)
{
    if (threadIdx.x == 0) {
        float ece = 0.f;
        for (int i = 0; i < N_BINS; ++i) {
            float cnt = bins[i];
            if (cnt > 0.f) {
                float sc  = fmaxf(cnt, 1.0f);
                float gap = fabsf(bins[15 + i] / sc - bins[30 + i] / sc);
                ece += gap * (cnt / n);
            }
        }
        out[0] = ece;
    }
}

extern "C" void kernel_launch(void* const* d_in, const int* in_sizes, int n_in,
                              void* d_out, int out_size, void* d_ws, size_t ws_size,
                              hipStream_t stream)
{
    const float* logits = (const float*)d_in[0];
    const int*   labels = (const int*)d_in[1];
    float* out  = (float*)d_out;
    float* bins = (float*)d_ws;

    const int n_rows = in_sizes[1];   // N = 2097152
    const int rows_per_sweep = GRID * ROWS;            // 49152
    const int niter = (n_rows + rows_per_sweep - 1) / rows_per_sweep;  // 43

    hipMemsetAsync(bins, 0, 45 * sizeof(float), stream);
    ece_pass1<<<GRID, 256, 0, stream>>>(logits, labels, bins, n_rows, niter);
    ece_final<<<1, 64, 0, stream>>>(bins, out, (float)n_rows);
}